// Round 1
// baseline (178.559 us; speedup 1.0000x reference)
//
#include <hip/hip_runtime.h>

#define NN 20000
#define KK 32
#define DD 256
#define HH 256
#define BN 16   // nodes per block

__global__ __launch_bounds__(256, 4) void hetegraph_fused_kernel(
    const float* __restrict__ embed,    // [V, D]
    const int*   __restrict__ node_ids, // [N]
    const int*   __restrict__ nb_ids,   // [N, K]
    const float* __restrict__ Ws,       // [D, H]
    const float* __restrict__ Wn,       // [D, H]
    const float* __restrict__ bias,     // [2H]
    float*       __restrict__ out)      // [N, 2H]
{
    __shared__ float As[BN][DD];  // gathered self embeddings
    __shared__ float An[BN][DD];  // mean-pooled neighbor embeddings

    const int tid  = threadIdx.x;
    const int wave = tid >> 6;
    const int lane = tid & 63;
    const int g0   = blockIdx.x * BN;

    // ---- Phase 1: gather + mean-pool into LDS ----
    // each wave handles BN/4 = 4 nodes; lane l covers f32 elements [4l, 4l+4)
    for (int n = wave; n < BN; n += 4) {
        const int g = g0 + n;
        const int self_row = node_ids[g];
        const float4 s = *(const float4*)&embed[(size_t)self_row * DD + lane * 4];

        float4 acc = make_float4(0.f, 0.f, 0.f, 0.f);
        #pragma unroll
        for (int k0 = 0; k0 < KK; k0 += 8) {
            float4 r[8];
            #pragma unroll
            for (int j = 0; j < 8; ++j) {
                const int row = nb_ids[g * KK + k0 + j];  // wave-uniform -> s_load
                r[j] = *(const float4*)&embed[(size_t)row * DD + lane * 4];
            }
            #pragma unroll
            for (int j = 0; j < 8; ++j) {
                acc.x += r[j].x; acc.y += r[j].y;
                acc.z += r[j].z; acc.w += r[j].w;
            }
        }
        const float inv = 1.0f / (float)KK;
        *(float4*)&As[n][lane * 4] = s;
        float4 m = make_float4(acc.x * inv, acc.y * inv, acc.z * inv, acc.w * inv);
        *(float4*)&An[n][lane * 4] = m;
    }
    __syncthreads();

    // ---- Phase 2: dual GEMM, thread h owns one output column ----
    const int h = tid;  // 0..255

    // pass 1: from_self = As @ Ws, bias[h], relu -> out[n][h]
    {
        float acc[BN];
        #pragma unroll
        for (int n = 0; n < BN; ++n) acc[n] = 0.f;

        for (int d0 = 0; d0 < DD; d0 += 4) {
            const float w0 = Ws[(d0 + 0) * HH + h];
            const float w1 = Ws[(d0 + 1) * HH + h];
            const float w2 = Ws[(d0 + 2) * HH + h];
            const float w3 = Ws[(d0 + 3) * HH + h];
            #pragma unroll
            for (int n = 0; n < BN; ++n) {
                const float4 a = *(const float4*)&As[n][d0];  // LDS broadcast
                acc[n] = fmaf(a.x, w0, acc[n]);
                acc[n] = fmaf(a.y, w1, acc[n]);
                acc[n] = fmaf(a.z, w2, acc[n]);
                acc[n] = fmaf(a.w, w3, acc[n]);
            }
        }
        const float b = bias[h];
        #pragma unroll
        for (int n = 0; n < BN; ++n) {
            const float v = acc[n] + b;
            out[(size_t)(g0 + n) * (2 * HH) + h] = v > 0.f ? v : 0.f;
        }
    }

    // pass 2: from_nb = An @ Wn, bias[H+h], relu -> out[n][H+h]
    {
        float acc[BN];
        #pragma unroll
        for (int n = 0; n < BN; ++n) acc[n] = 0.f;

        for (int d0 = 0; d0 < DD; d0 += 4) {
            const float w0 = Wn[(d0 + 0) * HH + h];
            const float w1 = Wn[(d0 + 1) * HH + h];
            const float w2 = Wn[(d0 + 2) * HH + h];
            const float w3 = Wn[(d0 + 3) * HH + h];
            #pragma unroll
            for (int n = 0; n < BN; ++n) {
                const float4 a = *(const float4*)&An[n][d0];  // LDS broadcast
                acc[n] = fmaf(a.x, w0, acc[n]);
                acc[n] = fmaf(a.y, w1, acc[n]);
                acc[n] = fmaf(a.z, w2, acc[n]);
                acc[n] = fmaf(a.w, w3, acc[n]);
            }
        }
        const float b = bias[HH + h];
        #pragma unroll
        for (int n = 0; n < BN; ++n) {
            const float v = acc[n] + b;
            out[(size_t)(g0 + n) * (2 * HH) + HH + h] = v > 0.f ? v : 0.f;
        }
    }
}

extern "C" void kernel_launch(void* const* d_in, const int* in_sizes, int n_in,
                              void* d_out, int out_size, void* d_ws, size_t ws_size,
                              hipStream_t stream) {
    const float* embed    = (const float*)d_in[0];
    const int*   node_ids = (const int*)d_in[1];
    const int*   nb_ids   = (const int*)d_in[2];
    const float* Ws       = (const float*)d_in[3];
    const float* Wn       = (const float*)d_in[4];
    const float* bias     = (const float*)d_in[5];
    float*       out      = (float*)d_out;

    dim3 grid(NN / BN);   // 20000/16 = 1250
    dim3 block(256);
    hetegraph_fused_kernel<<<grid, block, 0, stream>>>(
        embed, node_ids, nb_ids, Ws, Wn, bias, out);
}

// Round 2
// 148.654 us; speedup vs baseline: 1.2012x; 1.2012x over previous
//
#include <hip/hip_runtime.h>

#define VV 100000
#define NN 20000
#define KK 32
#define DD 256
#define HH 256

typedef __attribute__((ext_vector_type(8))) short bf16x8;
typedef __attribute__((ext_vector_type(4))) float f32x4;

__device__ __forceinline__ ushort f2bf(float f) {
    // round-to-nearest-even f32 -> bf16
    uint u = __float_as_uint(f);
    return (ushort)((u + 0x7FFFu + ((u >> 16) & 1u)) >> 16);
}

// ---------------- Kernel 1: W [D][H] f32 -> W^T [H][D] bf16 ----------------
__global__ __launch_bounds__(256) void k_prep_w(
    const float* __restrict__ Ws, const float* __restrict__ Wn,
    ushort* __restrict__ WT)   // [2][H][D] bf16
{
    __shared__ float t[64][65];
    const int tid = threadIdx.x;
    const float* src = (blockIdx.z == 0) ? Ws : Wn;
    ushort* dst = WT + (size_t)blockIdx.z * HH * DD;
    const int d0 = blockIdx.x * 64, h0 = blockIdx.y * 64;

    const int hl = tid & 63, dq = tid >> 6;
    #pragma unroll
    for (int i = 0; i < 16; ++i) {
        const int dl = dq * 16 + i;
        t[dl][hl] = src[(size_t)(d0 + dl) * HH + h0 + hl];   // coalesced read
    }
    __syncthreads();
    const int dl = tid & 63, hq = tid >> 6;
    #pragma unroll
    for (int i = 0; i < 16; ++i) {
        const int h2 = hq * 16 + i;
        dst[(size_t)(h0 + h2) * DD + d0 + dl] = f2bf(t[dl][h2]);  // coalesced write
    }
}

// ---------------- Kernel 2: gather + mean-pool -> A [N][512] bf16 ----------
// row g: [0,256) = self embedding, [256,512) = mean of K neighbor embeddings
__global__ __launch_bounds__(256, 4) void k_gather(
    const float* __restrict__ embed,
    const int*   __restrict__ node_ids,
    const int*   __restrict__ nb_ids,
    ushort*      __restrict__ A)
{
    const int wave = threadIdx.x >> 6;
    const int lane = threadIdx.x & 63;
    const int g = blockIdx.x * 4 + wave;     // one node per wave

    const int self_row = node_ids[g];
    const float4 s = *(const float4*)&embed[(size_t)self_row * DD + lane * 4];

    float4 acc = make_float4(0.f, 0.f, 0.f, 0.f);
    #pragma unroll
    for (int k0 = 0; k0 < KK; k0 += 8) {
        float4 r[8];
        #pragma unroll
        for (int j = 0; j < 8; ++j) {
            const int row = nb_ids[g * KK + k0 + j];      // wave-uniform
            r[j] = *(const float4*)&embed[(size_t)row * DD + lane * 4];
        }
        #pragma unroll
        for (int j = 0; j < 8; ++j) {
            acc.x += r[j].x; acc.y += r[j].y;
            acc.z += r[j].z; acc.w += r[j].w;
        }
    }
    const float inv = 1.0f / (float)KK;

    ushort4 ps = make_ushort4(f2bf(s.x), f2bf(s.y), f2bf(s.z), f2bf(s.w));
    ushort4 pn = make_ushort4(f2bf(acc.x * inv), f2bf(acc.y * inv),
                              f2bf(acc.z * inv), f2bf(acc.w * inv));
    *(ushort4*)&A[(size_t)g * 512 + lane * 4]       = ps;
    *(ushort4*)&A[(size_t)g * 512 + 256 + lane * 4] = pn;
}

// ---------------- Kernel 3: MFMA GEMM  out = relu([A_s@Ws | A_n@Wn] + bias) -
// block = 4 waves, 16 rows x 512 cols. wave w: half = w>>1 (0:self 1:nb),
// 128-col quarter = (w&1)*128. 8 column tiles of 16, K=256 in 8 steps of 32.
__global__ __launch_bounds__(256, 4) void k_gemm(
    const ushort* __restrict__ A,     // [N][512] bf16
    const ushort* __restrict__ WT,    // [2][H][D] bf16
    const float*  __restrict__ bias,  // [2H]
    float*        __restrict__ out)   // [N][2H]
{
    const int tid  = threadIdx.x;
    const int wave = tid >> 6;
    const int lane = tid & 63;
    const int g0   = blockIdx.x * 16;

    const int half = wave >> 1;         // 0 = self, 1 = nb
    const int colq = (wave & 1) * 128;  // column quarter within half
    const int r16  = lane & 15;         // A row / B col / C col
    const int kg   = lane >> 4;         // k-group (0..3), 8 bf16 each

    // A fragments: lane reads A[g0+r16][half*256 + ks*32 + kg*8 .. +8]
    const ushort* Ab = A + (size_t)(g0 + r16) * 512 + half * 256 + kg * 8;
    bf16x8 a[8];
    #pragma unroll
    for (int ks = 0; ks < 8; ++ks)
        a[ks] = *(const bf16x8*)(Ab + ks * 32);

    const ushort* Wb = WT + (size_t)half * HH * DD;

    f32x4 accs[8];
    #pragma unroll
    for (int ct = 0; ct < 8; ++ct) {
        const int c = colq + ct * 16 + r16;               // col within half
        const ushort* Bb = Wb + (size_t)c * DD + kg * 8;
        f32x4 acc = {0.f, 0.f, 0.f, 0.f};
        #pragma unroll
        for (int ks = 0; ks < 8; ++ks) {
            bf16x8 b = *(const bf16x8*)(Bb + ks * 32);
            acc = __builtin_amdgcn_mfma_f32_16x16x32_bf16(a[ks], b, acc, 0, 0, 0);
        }
        accs[ct] = acc;
    }

    // epilogue: bias + relu, D layout col=lane&15, row=(lane>>4)*4+reg
    #pragma unroll
    for (int ct = 0; ct < 8; ++ct) {
        const int cglob = half * HH + colq + ct * 16 + r16;
        const float bv = bias[cglob];
        #pragma unroll
        for (int r = 0; r < 4; ++r) {
            const int orow = kg * 4 + r;
            const float v = accs[ct][r] + bv;
            out[(size_t)(g0 + orow) * (2 * HH) + cglob] = v > 0.f ? v : 0.f;
        }
    }
}

// ---------------- Fallback (round-1 fused fp32 kernel) ---------------------
#define BN 16
__global__ __launch_bounds__(256, 4) void hetegraph_fused_kernel(
    const float* __restrict__ embed, const int* __restrict__ node_ids,
    const int* __restrict__ nb_ids, const float* __restrict__ Ws,
    const float* __restrict__ Wn, const float* __restrict__ bias,
    float* __restrict__ out)
{
    __shared__ float As[BN][DD];
    __shared__ float An[BN][DD];
    const int tid = threadIdx.x, wave = tid >> 6, lane = tid & 63;
    const int g0 = blockIdx.x * BN;
    for (int n = wave; n < BN; n += 4) {
        const int g = g0 + n;
        const int self_row = node_ids[g];
        const float4 s = *(const float4*)&embed[(size_t)self_row * DD + lane * 4];
        float4 acc = make_float4(0.f, 0.f, 0.f, 0.f);
        for (int k0 = 0; k0 < KK; k0 += 8) {
            float4 r[8];
            #pragma unroll
            for (int j = 0; j < 8; ++j) {
                const int row = nb_ids[g * KK + k0 + j];
                r[j] = *(const float4*)&embed[(size_t)row * DD + lane * 4];
            }
            #pragma unroll
            for (int j = 0; j < 8; ++j) {
                acc.x += r[j].x; acc.y += r[j].y; acc.z += r[j].z; acc.w += r[j].w;
            }
        }
        const float inv = 1.0f / (float)KK;
        *(float4*)&As[n][lane * 4] = s;
        float4 m = make_float4(acc.x * inv, acc.y * inv, acc.z * inv, acc.w * inv);
        *(float4*)&An[n][lane * 4] = m;
    }
    __syncthreads();
    const int h = tid;
    {
        float acc[BN];
        #pragma unroll
        for (int n = 0; n < BN; ++n) acc[n] = 0.f;
        for (int d0 = 0; d0 < DD; d0 += 4) {
            const float w0 = Ws[(d0+0)*HH+h], w1 = Ws[(d0+1)*HH+h];
            const float w2 = Ws[(d0+2)*HH+h], w3 = Ws[(d0+3)*HH+h];
            #pragma unroll
            for (int n = 0; n < BN; ++n) {
                const float4 a = *(const float4*)&As[n][d0];
                acc[n] = fmaf(a.x,w0,acc[n]); acc[n] = fmaf(a.y,w1,acc[n]);
                acc[n] = fmaf(a.z,w2,acc[n]); acc[n] = fmaf(a.w,w3,acc[n]);
            }
        }
        const float b = bias[h];
        #pragma unroll
        for (int n = 0; n < BN; ++n) {
            const float v = acc[n] + b;
            out[(size_t)(g0+n)*(2*HH) + h] = v > 0.f ? v : 0.f;
        }
    }
    {
        float acc[BN];
        #pragma unroll
        for (int n = 0; n < BN; ++n) acc[n] = 0.f;
        for (int d0 = 0; d0 < DD; d0 += 4) {
            const float w0 = Wn[(d0+0)*HH+h], w1 = Wn[(d0+1)*HH+h];
            const float w2 = Wn[(d0+2)*HH+h], w3 = Wn[(d0+3)*HH+h];
            #pragma unroll
            for (int n = 0; n < BN; ++n) {
                const float4 a = *(const float4*)&An[n][d0];
                acc[n] = fmaf(a.x,w0,acc[n]); acc[n] = fmaf(a.y,w1,acc[n]);
                acc[n] = fmaf(a.z,w2,acc[n]); acc[n] = fmaf(a.w,w3,acc[n]);
            }
        }
        const float b = bias[HH + h];
        #pragma unroll
        for (int n = 0; n < BN; ++n) {
            const float v = acc[n] + b;
            out[(size_t)(g0+n)*(2*HH) + HH + h] = v > 0.f ? v : 0.f;
        }
    }
}

extern "C" void kernel_launch(void* const* d_in, const int* in_sizes, int n_in,
                              void* d_out, int out_size, void* d_ws, size_t ws_size,
                              hipStream_t stream) {
    const float* embed    = (const float*)d_in[0];
    const int*   node_ids = (const int*)d_in[1];
    const int*   nb_ids   = (const int*)d_in[2];
    const float* Ws       = (const float*)d_in[3];
    const float* Wn       = (const float*)d_in[4];
    const float* bias     = (const float*)d_in[5];
    float*       out      = (float*)d_out;

    const size_t wt_bytes = 2ull * HH * DD * sizeof(ushort);          // 256 KB
    const size_t a_bytes  = (size_t)NN * 512 * sizeof(ushort);        // 20.48 MB

    if (ws_size < wt_bytes + a_bytes) {
        // fallback: round-1 fused fp32 kernel
        hetegraph_fused_kernel<<<dim3(NN / BN), dim3(256), 0, stream>>>(
            embed, node_ids, nb_ids, Ws, Wn, bias, out);
        return;
    }

    ushort* WT  = (ushort*)d_ws;
    ushort* Aws = (ushort*)((char*)d_ws + wt_bytes);

    k_prep_w<<<dim3(DD / 64, HH / 64, 2), dim3(256), 0, stream>>>(Ws, Wn, WT);
    k_gather<<<dim3(NN / 4), dim3(256), 0, stream>>>(embed, node_ids, nb_ids, Aws);
    k_gemm<<<dim3(NN / 16), dim3(256), 0, stream>>>(Aws, WT, bias, out);
}

// Round 3
// 118.562 us; speedup vs baseline: 1.5060x; 1.2538x over previous
//
#include <hip/hip_runtime.h>

#define VV 100000
#define NN 20000
#define KK 32
#define DD 256
#define HH 256
#define BN 16   // nodes per block in fused kernel

typedef __attribute__((ext_vector_type(8))) short bf16x8;
typedef __attribute__((ext_vector_type(4))) float f32x4;

__device__ __forceinline__ ushort f2bf(float f) {
    // round-to-nearest-even f32 -> bf16
    uint u = __float_as_uint(f);
    return (ushort)((u + 0x7FFFu + ((u >> 16) & 1u)) >> 16);
}
__device__ __forceinline__ float bf2f(ushort u) {
    return __uint_as_float(((uint)u) << 16);
}

// ---------------- Kernel 0: embed table f32 -> bf16 ------------------------
__global__ __launch_bounds__(256) void k_conv(
    const float* __restrict__ E, ushort* __restrict__ Eb)
{
    const size_t i = ((size_t)blockIdx.x * 256 + threadIdx.x) * 8;
    const float4 a = *(const float4*)&E[i];
    const float4 b = *(const float4*)&E[i + 4];
    bf16x8 v;
    v[0] = (short)f2bf(a.x); v[1] = (short)f2bf(a.y);
    v[2] = (short)f2bf(a.z); v[3] = (short)f2bf(a.w);
    v[4] = (short)f2bf(b.x); v[5] = (short)f2bf(b.y);
    v[6] = (short)f2bf(b.z); v[7] = (short)f2bf(b.w);
    *(bf16x8*)&Eb[i] = v;
}

// ---------------- Kernel 1: W [D][H] f32 -> W^T [H][D] bf16 ----------------
__global__ __launch_bounds__(256) void k_prep_w(
    const float* __restrict__ Ws, const float* __restrict__ Wn,
    ushort* __restrict__ WT)   // [2][H][D] bf16
{
    __shared__ float t[64][65];
    const int tid = threadIdx.x;
    const float* src = (blockIdx.z == 0) ? Ws : Wn;
    ushort* dst = WT + (size_t)blockIdx.z * HH * DD;
    const int d0 = blockIdx.x * 64, h0 = blockIdx.y * 64;

    const int hl = tid & 63, dq = tid >> 6;
    #pragma unroll
    for (int i = 0; i < 16; ++i) {
        const int dl = dq * 16 + i;
        t[dl][hl] = src[(size_t)(d0 + dl) * HH + h0 + hl];
    }
    __syncthreads();
    const int dl = tid & 63, hq = tid >> 6;
    #pragma unroll
    for (int i = 0; i < 16; ++i) {
        const int h2 = hq * 16 + i;
        dst[(size_t)(h0 + h2) * DD + d0 + dl] = f2bf(t[dl][h2]);
    }
}

// ---------------- Kernel 2: fused gather + mean-pool + MFMA GEMM -----------
// Block = 256 threads (4 waves), BN=16 nodes.
// Phase 1: each wave gathers+pools 4 nodes into LDS (bf16, XOR-swizzled).
// Phase 2: wave w -> half = w>>1 (self/nb), col quarter = (w&1)*128;
//          16x128 output via 8 col-tiles x 8 K-steps of mfma 16x16x32 bf16.
template<int EBF16>
__global__ __launch_bounds__(256, 4) void k_fused(
    const float*  __restrict__ Ef,       // f32 table (EBF16=0)
    const ushort* __restrict__ Eb,       // bf16 table (EBF16=1)
    const int*    __restrict__ node_ids,
    const int*    __restrict__ nb_ids,
    const ushort* __restrict__ WT,       // [2][H][D] bf16
    const float*  __restrict__ bias,     // [2H]
    float*        __restrict__ out)      // [N][2H]
{
    __shared__ ushort As[BN][DD];
    __shared__ ushort An[BN][DD];
    const int tid  = threadIdx.x;
    const int wave = tid >> 6;
    const int lane = tid & 63;
    const int g0   = blockIdx.x * BN;

    // ---- Phase 1 ----
    for (int n = wave; n < BN; n += 4) {
        const int g = g0 + n;
        const int srow = node_ids[g];
        const uint swz  = ((uint)(n & 7)) << 4;      // XOR on byte-in-row
        const uint boff = (uint)lane * 8;            // 8 B per lane
        ushort4 sv;
        float4 acc = make_float4(0.f, 0.f, 0.f, 0.f);

        if (EBF16) {
            sv = *(const ushort4*)&Eb[(size_t)srow * DD + lane * 4];
            #pragma unroll
            for (int k0 = 0; k0 < KK; k0 += 8) {
                ushort4 r[8];
                #pragma unroll
                for (int j = 0; j < 8; ++j) {
                    const int row = nb_ids[g * KK + k0 + j];   // wave-uniform
                    r[j] = *(const ushort4*)&Eb[(size_t)row * DD + lane * 4];
                }
                #pragma unroll
                for (int j = 0; j < 8; ++j) {
                    acc.x += bf2f(r[j].x); acc.y += bf2f(r[j].y);
                    acc.z += bf2f(r[j].z); acc.w += bf2f(r[j].w);
                }
            }
        } else {
            const float4 s = *(const float4*)&Ef[(size_t)srow * DD + lane * 4];
            sv = make_ushort4(f2bf(s.x), f2bf(s.y), f2bf(s.z), f2bf(s.w));
            #pragma unroll
            for (int k0 = 0; k0 < KK; k0 += 8) {
                float4 r[8];
                #pragma unroll
                for (int j = 0; j < 8; ++j) {
                    const int row = nb_ids[g * KK + k0 + j];
                    r[j] = *(const float4*)&Ef[(size_t)row * DD + lane * 4];
                }
                #pragma unroll
                for (int j = 0; j < 8; ++j) {
                    acc.x += r[j].x; acc.y += r[j].y;
                    acc.z += r[j].z; acc.w += r[j].w;
                }
            }
        }
        const float inv = 1.0f / (float)KK;
        const ushort4 nv = make_ushort4(f2bf(acc.x * inv), f2bf(acc.y * inv),
                                        f2bf(acc.z * inv), f2bf(acc.w * inv));
        *(ushort4*)((char*)&As[n][0] + (boff ^ swz)) = sv;
        *(ushort4*)((char*)&An[n][0] + (boff ^ swz)) = nv;
    }
    __syncthreads();

    // ---- Phase 2 ----
    const int half = wave >> 1;          // 0 = self, 1 = nb
    const int colq = (wave & 1) * 128;
    const int r16  = lane & 15;          // A row / B col / C col
    const int kg   = lane >> 4;          // k-group (8 bf16 each)
    const uint rswz = ((uint)(r16 & 7)) << 4;
    const char* Arow = (const char*)(half ? &An[r16][0] : &As[r16][0]);

    bf16x8 a[8];
    #pragma unroll
    for (int ks = 0; ks < 8; ++ks) {
        const uint off = (uint)(ks * 64 + kg * 16);
        a[ks] = *(const bf16x8*)(Arow + (off ^ rswz));
    }

    const ushort* Wb = WT + (size_t)half * HH * DD;
    f32x4 accs[8];
    #pragma unroll
    for (int ct = 0; ct < 8; ++ct) {
        const int c = colq + ct * 16 + r16;
        const ushort* Bb = Wb + (size_t)c * DD + kg * 8;
        f32x4 acc = {0.f, 0.f, 0.f, 0.f};
        #pragma unroll
        for (int ks = 0; ks < 8; ++ks) {
            const bf16x8 b = *(const bf16x8*)(Bb + ks * 32);
            acc = __builtin_amdgcn_mfma_f32_16x16x32_bf16(a[ks], b, acc, 0, 0, 0);
        }
        accs[ct] = acc;
    }

    // epilogue: bias + relu; C/D layout col=lane&15, row=(lane>>4)*4+reg
    #pragma unroll
    for (int ct = 0; ct < 8; ++ct) {
        const int cglob = half * HH + colq + ct * 16 + r16;
        const float bv = bias[cglob];
        #pragma unroll
        for (int r = 0; r < 4; ++r) {
            const float v = accs[ct][r] + bv;
            out[(size_t)(g0 + kg * 4 + r) * (2 * HH) + cglob] = v > 0.f ? v : 0.f;
        }
    }
}

// ---------------- Ultimate fallback (round-1 fused fp32 kernel) ------------
__global__ __launch_bounds__(256, 4) void hetegraph_fused_kernel(
    const float* __restrict__ embed, const int* __restrict__ node_ids,
    const int* __restrict__ nb_ids, const float* __restrict__ Ws,
    const float* __restrict__ Wn, const float* __restrict__ bias,
    float* __restrict__ out)
{
    __shared__ float As[BN][DD];
    __shared__ float An[BN][DD];
    const int tid = threadIdx.x, wave = tid >> 6, lane = tid & 63;
    const int g0 = blockIdx.x * BN;
    for (int n = wave; n < BN; n += 4) {
        const int g = g0 + n;
        const int self_row = node_ids[g];
        const float4 s = *(const float4*)&embed[(size_t)self_row * DD + lane * 4];
        float4 acc = make_float4(0.f, 0.f, 0.f, 0.f);
        for (int k0 = 0; k0 < KK; k0 += 8) {
            float4 r[8];
            #pragma unroll
            for (int j = 0; j < 8; ++j) {
                const int row = nb_ids[g * KK + k0 + j];
                r[j] = *(const float4*)&embed[(size_t)row * DD + lane * 4];
            }
            #pragma unroll
            for (int j = 0; j < 8; ++j) {
                acc.x += r[j].x; acc.y += r[j].y; acc.z += r[j].z; acc.w += r[j].w;
            }
        }
        const float inv = 1.0f / (float)KK;
        *(float4*)&As[n][lane * 4] = s;
        float4 m = make_float4(acc.x * inv, acc.y * inv, acc.z * inv, acc.w * inv);
        *(float4*)&An[n][lane * 4] = m;
    }
    __syncthreads();
    const int h = tid;
    {
        float acc[BN];
        #pragma unroll
        for (int n = 0; n < BN; ++n) acc[n] = 0.f;
        for (int d0 = 0; d0 < DD; d0 += 4) {
            const float w0 = Ws[(d0+0)*HH+h], w1 = Ws[(d0+1)*HH+h];
            const float w2 = Ws[(d0+2)*HH+h], w3 = Ws[(d0+3)*HH+h];
            #pragma unroll
            for (int n = 0; n < BN; ++n) {
                const float4 a = *(const float4*)&As[n][d0];
                acc[n] = fmaf(a.x,w0,acc[n]); acc[n] = fmaf(a.y,w1,acc[n]);
                acc[n] = fmaf(a.z,w2,acc[n]); acc[n] = fmaf(a.w,w3,acc[n]);
            }
        }
        const float b = bias[h];
        #pragma unroll
        for (int n = 0; n < BN; ++n) {
            const float v = acc[n] + b;
            out[(size_t)(g0+n)*(2*HH) + h] = v > 0.f ? v : 0.f;
        }
    }
    {
        float acc[BN];
        #pragma unroll
        for (int n = 0; n < BN; ++n) acc[n] = 0.f;
        for (int d0 = 0; d0 < DD; d0 += 4) {
            const float w0 = Wn[(d0+0)*HH+h], w1 = Wn[(d0+1)*HH+h];
            const float w2 = Wn[(d0+2)*HH+h], w3 = Wn[(d0+3)*HH+h];
            #pragma unroll
            for (int n = 0; n < BN; ++n) {
                const float4 a = *(const float4*)&An[n][d0];
                acc[n] = fmaf(a.x,w0,acc[n]); acc[n] = fmaf(a.y,w1,acc[n]);
                acc[n] = fmaf(a.z,w2,acc[n]); acc[n] = fmaf(a.w,w3,acc[n]);
            }
        }
        const float b = bias[HH + h];
        #pragma unroll
        for (int n = 0; n < BN; ++n) {
            const float v = acc[n] + b;
            out[(size_t)(g0+n)*(2*HH) + HH + h] = v > 0.f ? v : 0.f;
        }
    }
}

extern "C" void kernel_launch(void* const* d_in, const int* in_sizes, int n_in,
                              void* d_out, int out_size, void* d_ws, size_t ws_size,
                              hipStream_t stream) {
    const float* embed    = (const float*)d_in[0];
    const int*   node_ids = (const int*)d_in[1];
    const int*   nb_ids   = (const int*)d_in[2];
    const float* Ws       = (const float*)d_in[3];
    const float* Wn       = (const float*)d_in[4];
    const float* bias     = (const float*)d_in[5];
    float*       out      = (float*)d_out;

    const size_t eb_bytes = (size_t)VV * DD * sizeof(ushort);   // 51.2 MB
    const size_t wt_bytes = 2ull * HH * DD * sizeof(ushort);    // 256 KB

    if (ws_size >= eb_bytes + wt_bytes) {
        ushort* Eb = (ushort*)d_ws;
        ushort* WT = (ushort*)((char*)d_ws + eb_bytes);
        k_conv<<<dim3(VV * DD / 2048), dim3(256), 0, stream>>>(embed, Eb);
        k_prep_w<<<dim3(DD / 64, HH / 64, 2), dim3(256), 0, stream>>>(Ws, Wn, WT);
        k_fused<1><<<dim3(NN / BN), dim3(256), 0, stream>>>(
            nullptr, Eb, node_ids, nb_ids, WT, bias, out);
    } else if (ws_size >= wt_bytes) {
        ushort* WT = (ushort*)d_ws;
        k_prep_w<<<dim3(DD / 64, HH / 64, 2), dim3(256), 0, stream>>>(Ws, Wn, WT);
        k_fused<0><<<dim3(NN / BN), dim3(256), 0, stream>>>(
            embed, nullptr, node_ids, nb_ids, WT, bias, out);
    } else {
        hetegraph_fused_kernel<<<dim3(NN / BN), dim3(256), 0, stream>>>(
            embed, node_ids, nb_ids, Ws, Wn, bias, out);
    }
}

// Round 5
// 112.435 us; speedup vs baseline: 1.5881x; 1.0545x over previous
//
#include <hip/hip_runtime.h>

#define VV 100000
#define NN 20000
#define KK 32
#define DD 256
#define HH 256
#define BN 16   // nodes per block in fused kernel

typedef __attribute__((ext_vector_type(8))) short bf16x8;
typedef __attribute__((ext_vector_type(4))) float f32x4;

__device__ __forceinline__ ushort f2bf(float f) {
    // round-to-nearest-even f32 -> bf16
    uint u = __float_as_uint(f);
    return (ushort)((u + 0x7FFFu + ((u >> 16) & 1u)) >> 16);
}
__device__ __forceinline__ float bf2f(ushort u) {
    return __uint_as_float(((uint)u) << 16);
}

// ---------------- Kernel 0: embed table f32 -> bf16 ------------------------
// Non-temporal reads: the f32 table is single-use; keep L3 for the bf16 table.
__global__ __launch_bounds__(256) void k_conv(
    const float* __restrict__ E, ushort* __restrict__ Eb)
{
    const size_t i = ((size_t)blockIdx.x * 256 + threadIdx.x) * 8;
    const f32x4 a = __builtin_nontemporal_load((const f32x4*)&E[i]);
    const f32x4 b = __builtin_nontemporal_load((const f32x4*)&E[i + 4]);
    bf16x8 v;
    v[0] = (short)f2bf(a.x); v[1] = (short)f2bf(a.y);
    v[2] = (short)f2bf(a.z); v[3] = (short)f2bf(a.w);
    v[4] = (short)f2bf(b.x); v[5] = (short)f2bf(b.y);
    v[6] = (short)f2bf(b.z); v[7] = (short)f2bf(b.w);
    *(bf16x8*)&Eb[i] = v;
}

// ---------------- Kernel 1: W [D][H] f32 -> W^T [H][D] bf16 ----------------
__global__ __launch_bounds__(256) void k_prep_w(
    const float* __restrict__ Ws, const float* __restrict__ Wn,
    ushort* __restrict__ WT)   // [2][H][D] bf16
{
    __shared__ float t[64][65];
    const int tid = threadIdx.x;
    const float* src = (blockIdx.z == 0) ? Ws : Wn;
    ushort* dst = WT + (size_t)blockIdx.z * HH * DD;
    const int d0 = blockIdx.x * 64, h0 = blockIdx.y * 64;

    const int hl = tid & 63, dq = tid >> 6;
    #pragma unroll
    for (int i = 0; i < 16; ++i) {
        const int dl = dq * 16 + i;
        t[dl][hl] = src[(size_t)(d0 + dl) * HH + h0 + hl];
    }
    __syncthreads();
    const int dl = tid & 63, hq = tid >> 6;
    #pragma unroll
    for (int i = 0; i < 16; ++i) {
        const int h2 = hq * 16 + i;
        dst[(size_t)(h0 + h2) * DD + d0 + dl] = f2bf(t[dl][h2]);
    }
}

// ---------------- Kernel 2: fused gather + mean-pool + MFMA GEMM -----------
// Block = 256 threads (4 waves), BN=16 nodes.
// Phase 1: each wave gathers+pools 4 nodes into LDS (bf16, XOR-swizzled);
//          16 row-loads outstanding per window (2 windows per node).
// Phase 2: wave w -> half = w>>1 (self/nb), col quarter = (w&1)*128;
//          16x128 output via 8 col-tiles x 8 K-steps of mfma 16x16x32 bf16.
template<int EBF16>
__global__ __launch_bounds__(256, 4) void k_fused(
    const float*  __restrict__ Ef,       // f32 table (EBF16=0)
    const ushort* __restrict__ Eb,       // bf16 table (EBF16=1)
    const int*    __restrict__ node_ids,
    const int*    __restrict__ nb_ids,
    const ushort* __restrict__ WT,       // [2][H][D] bf16
    const float*  __restrict__ bias,     // [2H]
    float*        __restrict__ out)      // [N][2H]
{
    __shared__ ushort As[BN][DD];
    __shared__ ushort An[BN][DD];
    const int tid  = threadIdx.x;
    const int wave = tid >> 6;
    const int lane = tid & 63;
    const int g0   = blockIdx.x * BN;

    // ---- Phase 1 ----
    for (int n = wave; n < BN; n += 4) {
        const int g = g0 + n;
        const int srow = node_ids[g];
        const uint swz  = ((uint)(n & 7)) << 4;      // XOR on byte-in-row
        const uint boff = (uint)lane * 8;            // 8 B per lane
        ushort4 sv;
        float4 acc = make_float4(0.f, 0.f, 0.f, 0.f);

        if (EBF16) {
            sv = *(const ushort4*)&Eb[(size_t)srow * DD + lane * 4];
            #pragma unroll
            for (int w = 0; w < 2; ++w) {
                ushort4 r[16];
                #pragma unroll
                for (int j = 0; j < 16; ++j) {
                    const int row = nb_ids[g * KK + w * 16 + j];  // wave-uniform
                    r[j] = *(const ushort4*)&Eb[(size_t)row * DD + lane * 4];
                }
                #pragma unroll
                for (int j = 0; j < 16; ++j) {
                    acc.x += bf2f(r[j].x); acc.y += bf2f(r[j].y);
                    acc.z += bf2f(r[j].z); acc.w += bf2f(r[j].w);
                }
            }
        } else {
            const float4 s = *(const float4*)&Ef[(size_t)srow * DD + lane * 4];
            sv = make_ushort4(f2bf(s.x), f2bf(s.y), f2bf(s.z), f2bf(s.w));
            #pragma unroll
            for (int k0 = 0; k0 < KK; k0 += 8) {
                float4 r[8];
                #pragma unroll
                for (int j = 0; j < 8; ++j) {
                    const int row = nb_ids[g * KK + k0 + j];
                    r[j] = *(const float4*)&Ef[(size_t)row * DD + lane * 4];
                }
                #pragma unroll
                for (int j = 0; j < 8; ++j) {
                    acc.x += r[j].x; acc.y += r[j].y;
                    acc.z += r[j].z; acc.w += r[j].w;
                }
            }
        }
        const float inv = 1.0f / (float)KK;
        const ushort4 nv = make_ushort4(f2bf(acc.x * inv), f2bf(acc.y * inv),
                                        f2bf(acc.z * inv), f2bf(acc.w * inv));
        *(ushort4*)((char*)&As[n][0] + (boff ^ swz)) = sv;
        *(ushort4*)((char*)&An[n][0] + (boff ^ swz)) = nv;
    }
    __syncthreads();

    // ---- Phase 2 ----
    const int half = wave >> 1;          // 0 = self, 1 = nb
    const int colq = (wave & 1) * 128;
    const int r16  = lane & 15;          // A row / B col / C col
    const int kg   = lane >> 4;          // k-group (8 bf16 each)
    const uint rswz = ((uint)(r16 & 7)) << 4;
    const char* Arow = (const char*)(half ? &An[r16][0] : &As[r16][0]);

    bf16x8 a[8];
    #pragma unroll
    for (int ks = 0; ks < 8; ++ks) {
        const uint off = (uint)(ks * 64 + kg * 16);
        a[ks] = *(const bf16x8*)(Arow + (off ^ rswz));
    }

    const ushort* Wb = WT + (size_t)half * HH * DD;
    f32x4 accs[8];
    #pragma unroll
    for (int ct = 0; ct < 8; ++ct) {
        const int c = colq + ct * 16 + r16;
        const ushort* Bb = Wb + (size_t)c * DD + kg * 8;
        f32x4 acc = {0.f, 0.f, 0.f, 0.f};
        #pragma unroll
        for (int ks = 0; ks < 8; ++ks) {
            const bf16x8 b = *(const bf16x8*)(Bb + ks * 32);
            acc = __builtin_amdgcn_mfma_f32_16x16x32_bf16(a[ks], b, acc, 0, 0, 0);
        }
        accs[ct] = acc;
    }

    // epilogue: bias + relu; C/D layout col=lane&15, row=(lane>>4)*4+reg
    #pragma unroll
    for (int ct = 0; ct < 8; ++ct) {
        const int cglob = half * HH + colq + ct * 16 + r16;
        const float bv = bias[cglob];
        #pragma unroll
        for (int r = 0; r < 4; ++r) {
            const float v = accs[ct][r] + bv;
            out[(size_t)(g0 + kg * 4 + r) * (2 * HH) + cglob] = v > 0.f ? v : 0.f;
        }
    }
}

// ---------------- Ultimate fallback (round-1 fused fp32 kernel) ------------
__global__ __launch_bounds__(256, 4) void hetegraph_fused_kernel(
    const float* __restrict__ embed, const int* __restrict__ node_ids,
    const int* __restrict__ nb_ids, const float* __restrict__ Ws,
    const float* __restrict__ Wn, const float* __restrict__ bias,
    float* __restrict__ out)
{
    __shared__ float As[BN][DD];
    __shared__ float An[BN][DD];
    const int tid = threadIdx.x, wave = tid >> 6, lane = tid & 63;
    const int g0 = blockIdx.x * BN;
    for (int n = wave; n < BN; n += 4) {
        const int g = g0 + n;
        const int self_row = node_ids[g];
        const float4 s = *(const float4*)&embed[(size_t)self_row * DD + lane * 4];
        float4 acc = make_float4(0.f, 0.f, 0.f, 0.f);
        for (int k0 = 0; k0 < KK; k0 += 8) {
            float4 r[8];
            #pragma unroll
            for (int j = 0; j < 8; ++j) {
                const int row = nb_ids[g * KK + k0 + j];
                r[j] = *(const float4*)&embed[(size_t)row * DD + lane * 4];
            }
            #pragma unroll
            for (int j = 0; j < 8; ++j) {
                acc.x += r[j].x; acc.y += r[j].y; acc.z += r[j].z; acc.w += r[j].w;
            }
        }
        const float inv = 1.0f / (float)KK;
        *(float4*)&As[n][lane * 4] = s;
        float4 m = make_float4(acc.x * inv, acc.y * inv, acc.z * inv, acc.w * inv);
        *(float4*)&An[n][lane * 4] = m;
    }
    __syncthreads();
    const int h = tid;
    {
        float acc[BN];
        #pragma unroll
        for (int n = 0; n < BN; ++n) acc[n] = 0.f;
        for (int d0 = 0; d0 < DD; d0 += 4) {
            const float w0 = Ws[(d0+0)*HH+h], w1 = Ws[(d0+1)*HH+h];
            const float w2 = Ws[(d0+2)*HH+h], w3 = Ws[(d0+3)*HH+h];
            #pragma unroll
            for (int n = 0; n < BN; ++n) {
                const float4 a = *(const float4*)&As[n][d0];
                acc[n] = fmaf(a.x,w0,acc[n]); acc[n] = fmaf(a.y,w1,acc[n]);
                acc[n] = fmaf(a.z,w2,acc[n]); acc[n] = fmaf(a.w,w3,acc[n]);
            }
        }
        const float b = bias[h];
        #pragma unroll
        for (int n = 0; n < BN; ++n) {
            const float v = acc[n] + b;
            out[(size_t)(g0+n)*(2*HH) + h] = v > 0.f ? v : 0.f;
        }
    }
    {
        float acc[BN];
        #pragma unroll
        for (int n = 0; n < BN; ++n) acc[n] = 0.f;
        for (int d0 = 0; d0 < DD; d0 += 4) {
            const float w0 = Wn[(d0+0)*HH+h], w1 = Wn[(d0+1)*HH+h];
            const float w2 = Wn[(d0+2)*HH+h], w3 = Wn[(d0+3)*HH+h];
            #pragma unroll
            for (int n = 0; n < BN; ++n) {
                const float4 a = *(const float4*)&An[n][d0];
                acc[n] = fmaf(a.x,w0,acc[n]); acc[n] = fmaf(a.y,w1,acc[n]);
                acc[n] = fmaf(a.z,w2,acc[n]); acc[n] = fmaf(a.w,w3,acc[n]);
            }
        }
        const float b = bias[HH + h];
        #pragma unroll
        for (int n = 0; n < BN; ++n) {
            const float v = acc[n] + b;
            out[(size_t)(g0+n)*(2*HH) + HH + h] = v > 0.f ? v : 0.f;
        }
    }
}

extern "C" void kernel_launch(void* const* d_in, const int* in_sizes, int n_in,
                              void* d_out, int out_size, void* d_ws, size_t ws_size,
                              hipStream_t stream) {
    const float* embed    = (const float*)d_in[0];
    const int*   node_ids = (const int*)d_in[1];
    const int*   nb_ids   = (const int*)d_in[2];
    const float* Ws       = (const float*)d_in[3];
    const float* Wn       = (const float*)d_in[4];
    const float* bias     = (const float*)d_in[5];
    float*       out      = (float*)d_out;

    const size_t eb_bytes = (size_t)VV * DD * sizeof(ushort);   // 51.2 MB
    const size_t wt_bytes = 2ull * HH * DD * sizeof(ushort);    // 256 KB

    if (ws_size >= eb_bytes + wt_bytes) {
        ushort* Eb = (ushort*)d_ws;
        ushort* WT = (ushort*)((char*)d_ws + eb_bytes);
        k_conv<<<dim3(VV * DD / 2048), dim3(256), 0, stream>>>(embed, Eb);
        k_prep_w<<<dim3(DD / 64, HH / 64, 2), dim3(256), 0, stream>>>(Ws, Wn, WT);
        k_fused<1><<<dim3(NN / BN), dim3(256), 0, stream>>>(
            nullptr, Eb, node_ids, nb_ids, WT, bias, out);
    } else if (ws_size >= wt_bytes) {
        ushort* WT = (ushort*)d_ws;
        k_prep_w<<<dim3(DD / 64, HH / 64, 2), dim3(256), 0, stream>>>(Ws, Wn, WT);
        k_fused<0><<<dim3(NN / BN), dim3(256), 0, stream>>>(
            embed, nullptr, node_ids, nb_ids, WT, bias, out);
    } else {
        hetegraph_fused_kernel<<<dim3(NN / BN), dim3(256), 0, stream>>>(
            embed, node_ids, nb_ids, Ws, Wn, bias, out);
    }
}

// Round 6
// 108.268 us; speedup vs baseline: 1.6492x; 1.0385x over previous
//
#include <hip/hip_runtime.h>

#define VV 100000
#define NN 20000
#define KK 32
#define DD 256
#define HH 256
#define BN 16   // nodes per block in fused kernel

typedef __attribute__((ext_vector_type(8))) short bf16x8;
typedef __attribute__((ext_vector_type(4))) float f32x4;

__device__ __forceinline__ ushort f2bf(float f) {
    // round-to-nearest-even f32 -> bf16
    uint u = __float_as_uint(f);
    return (ushort)((u + 0x7FFFu + ((u >> 16) & 1u)) >> 16);
}
__device__ __forceinline__ float bf2f(ushort u) {
    return __uint_as_float(((uint)u) << 16);
}

// ---------------- Kernel 0: embed table f32 -> bf16 ------------------------
// Non-temporal reads: the f32 table is single-use; keep L3 for the bf16 table.
__global__ __launch_bounds__(256) void k_conv(
    const float* __restrict__ E, ushort* __restrict__ Eb)
{
    const size_t i = ((size_t)blockIdx.x * 256 + threadIdx.x) * 8;
    const f32x4 a = __builtin_nontemporal_load((const f32x4*)&E[i]);
    const f32x4 b = __builtin_nontemporal_load((const f32x4*)&E[i + 4]);
    bf16x8 v;
    v[0] = (short)f2bf(a.x); v[1] = (short)f2bf(a.y);
    v[2] = (short)f2bf(a.z); v[3] = (short)f2bf(a.w);
    v[4] = (short)f2bf(b.x); v[5] = (short)f2bf(b.y);
    v[6] = (short)f2bf(b.z); v[7] = (short)f2bf(b.w);
    *(bf16x8*)&Eb[i] = v;
}

// ---------------- Kernel 1: W [D][H] f32 -> W^T [H][D] bf16 ----------------
__global__ __launch_bounds__(256) void k_prep_w(
    const float* __restrict__ Ws, const float* __restrict__ Wn,
    ushort* __restrict__ WT)   // [2][H][D] bf16
{
    __shared__ float t[64][65];
    const int tid = threadIdx.x;
    const float* src = (blockIdx.z == 0) ? Ws : Wn;
    ushort* dst = WT + (size_t)blockIdx.z * HH * DD;
    const int d0 = blockIdx.x * 64, h0 = blockIdx.y * 64;

    const int hl = tid & 63, dq = tid >> 6;
    #pragma unroll
    for (int i = 0; i < 16; ++i) {
        const int dl = dq * 16 + i;
        t[dl][hl] = src[(size_t)(d0 + dl) * HH + h0 + hl];
    }
    __syncthreads();
    const int dl = tid & 63, hq = tid >> 6;
    #pragma unroll
    for (int i = 0; i < 16; ++i) {
        const int h2 = hq * 16 + i;
        dst[(size_t)(h0 + h2) * DD + d0 + dl] = f2bf(t[dl][h2]);
    }
}

// ---------------- Kernel 2: fused gather + mean-pool + MFMA GEMM -----------
// Block = 256 threads (4 waves), BN=16 nodes.
// Phase 1 (EBF16=1): 16 B/lane loads -> 32 lanes cover one 512 B row, so one
//   load instruction fetches TWO neighbor rows (lo half = even id, hi half =
//   odd id). One 16-deep window = all 32 neighbors of a node in flight.
//   Cross-half __shfl_xor(32) completes the pool. Self row rides the same
//   window (both halves load it; lo half stores it).
// Phase 2: wave w -> half = w>>1 (self/nb), col quarter = (w&1)*128;
//          16x128 output via 8 col-tiles x 8 K-steps of mfma 16x16x32 bf16.
template<int EBF16>
__global__ __launch_bounds__(256, 4) void k_fused(
    const float*  __restrict__ Ef,       // f32 table (EBF16=0)
    const ushort* __restrict__ Eb,       // bf16 table (EBF16=1)
    const int*    __restrict__ node_ids,
    const int*    __restrict__ nb_ids,
    const ushort* __restrict__ WT,       // [2][H][D] bf16
    const float*  __restrict__ bias,     // [2H]
    float*        __restrict__ out)      // [N][2H]
{
    __shared__ ushort As[BN][DD];
    __shared__ ushort An[BN][DD];
    const int tid  = threadIdx.x;
    const int wave = tid >> 6;
    const int lane = tid & 63;
    const int g0   = blockIdx.x * BN;

    // ---- Phase 1 ----
    if (EBF16) {
        const int sub = lane >> 5;       // 0 = lo half-wave, 1 = hi half-wave
        const int l31 = lane & 31;
        const uint boff = (uint)l31 * 16;  // 16 B per lane, 32 lanes per row
        for (int n = wave; n < BN; n += 4) {
            const int g = g0 + n;
            const int base = g * KK;
            const uint swz = ((uint)(n & 7)) << 4;

            // self row (both halves load it; redundant hi-half hits L2)
            const int srow = node_ids[g];
            const bf16x8 sv = *(const bf16x8*)&Eb[((size_t)(uint)srow << 8) + l31 * 8];

            // all 32 neighbor rows in one window of 16 paired loads
            bf16x8 r[16];
            #pragma unroll
            for (int j = 0; j < 16; ++j) {
                const int rlo = nb_ids[base + 2 * j];       // wave-uniform s_load
                const int rhi = nb_ids[base + 2 * j + 1];   // wave-uniform s_load
                const int row = sub ? rhi : rlo;            // cndmask
                r[j] = *(const bf16x8*)&Eb[((size_t)(uint)row << 8) + l31 * 8];
            }
            float acc[8];
            #pragma unroll
            for (int e = 0; e < 8; ++e) acc[e] = 0.f;
            #pragma unroll
            for (int j = 0; j < 16; ++j) {
                #pragma unroll
                for (int e = 0; e < 8; ++e)
                    acc[e] += bf2f((ushort)r[j][e]);
            }
            // combine even-row partial (lo half) with odd-row partial (hi half)
            #pragma unroll
            for (int e = 0; e < 8; ++e)
                acc[e] += __shfl_xor(acc[e], 32);

            const float inv = 1.0f / (float)KK;
            bf16x8 nv;
            #pragma unroll
            for (int e = 0; e < 8; ++e)
                nv[e] = (short)f2bf(acc[e] * inv);

            // lo half stores self row, hi half stores pooled row (swizzled)
            if (sub == 0) {
                *(bf16x8*)((char*)&As[n][0] + (boff ^ swz)) = sv;
            } else {
                *(bf16x8*)((char*)&An[n][0] + (boff ^ swz)) = nv;
            }
        }
    } else {
        for (int n = wave; n < BN; n += 4) {
            const int g = g0 + n;
            const int srow = node_ids[g];
            const uint swz  = ((uint)(n & 7)) << 4;
            const uint boff = (uint)lane * 8;
            const float4 s = *(const float4*)&Ef[(size_t)srow * DD + lane * 4];
            ushort4 sv = make_ushort4(f2bf(s.x), f2bf(s.y), f2bf(s.z), f2bf(s.w));
            float4 acc = make_float4(0.f, 0.f, 0.f, 0.f);
            #pragma unroll
            for (int k0 = 0; k0 < KK; k0 += 8) {
                float4 r[8];
                #pragma unroll
                for (int j = 0; j < 8; ++j) {
                    const int row = nb_ids[g * KK + k0 + j];
                    r[j] = *(const float4*)&Ef[(size_t)row * DD + lane * 4];
                }
                #pragma unroll
                for (int j = 0; j < 8; ++j) {
                    acc.x += r[j].x; acc.y += r[j].y;
                    acc.z += r[j].z; acc.w += r[j].w;
                }
            }
            const float inv = 1.0f / (float)KK;
            const ushort4 nv = make_ushort4(f2bf(acc.x * inv), f2bf(acc.y * inv),
                                            f2bf(acc.z * inv), f2bf(acc.w * inv));
            *(ushort4*)((char*)&As[n][0] + (boff ^ swz)) = sv;
            *(ushort4*)((char*)&An[n][0] + (boff ^ swz)) = nv;
        }
    }
    __syncthreads();

    // ---- Phase 2 ----
    const int half = wave >> 1;          // 0 = self, 1 = nb
    const int colq = (wave & 1) * 128;
    const int r16  = lane & 15;          // A row / B col / C col
    const int kg   = lane >> 4;          // k-group (8 bf16 each)
    const uint rswz = ((uint)(r16 & 7)) << 4;
    const char* Arow = (const char*)(half ? &An[r16][0] : &As[r16][0]);

    bf16x8 a[8];
    #pragma unroll
    for (int ks = 0; ks < 8; ++ks) {
        const uint off = (uint)(ks * 64 + kg * 16);
        a[ks] = *(const bf16x8*)(Arow + (off ^ rswz));
    }

    const ushort* Wb = WT + (size_t)half * HH * DD;
    f32x4 accs[8];
    #pragma unroll
    for (int ct = 0; ct < 8; ++ct) {
        const int c = colq + ct * 16 + r16;
        const ushort* Bb = Wb + (size_t)c * DD + kg * 8;
        f32x4 acc = {0.f, 0.f, 0.f, 0.f};
        #pragma unroll
        for (int ks = 0; ks < 8; ++ks) {
            const bf16x8 b = *(const bf16x8*)(Bb + ks * 32);
            acc = __builtin_amdgcn_mfma_f32_16x16x32_bf16(a[ks], b, acc, 0, 0, 0);
        }
        accs[ct] = acc;
    }

    // epilogue: bias + relu; C/D layout col=lane&15, row=(lane>>4)*4+reg
    #pragma unroll
    for (int ct = 0; ct < 8; ++ct) {
        const int cglob = half * HH + colq + ct * 16 + r16;
        const float bv = bias[cglob];
        #pragma unroll
        for (int r = 0; r < 4; ++r) {
            const float v = accs[ct][r] + bv;
            out[(size_t)(g0 + kg * 4 + r) * (2 * HH) + cglob] = v > 0.f ? v : 0.f;
        }
    }
}

// ---------------- Ultimate fallback (round-1 fused fp32 kernel) ------------
__global__ __launch_bounds__(256, 4) void hetegraph_fused_kernel(
    const float* __restrict__ embed, const int* __restrict__ node_ids,
    const int* __restrict__ nb_ids, const float* __restrict__ Ws,
    const float* __restrict__ Wn, const float* __restrict__ bias,
    float* __restrict__ out)
{
    __shared__ float As[BN][DD];
    __shared__ float An[BN][DD];
    const int tid = threadIdx.x, wave = tid >> 6, lane = tid & 63;
    const int g0 = blockIdx.x * BN;
    for (int n = wave; n < BN; n += 4) {
        const int g = g0 + n;
        const int self_row = node_ids[g];
        const float4 s = *(const float4*)&embed[(size_t)self_row * DD + lane * 4];
        float4 acc = make_float4(0.f, 0.f, 0.f, 0.f);
        for (int k0 = 0; k0 < KK; k0 += 8) {
            float4 r[8];
            #pragma unroll
            for (int j = 0; j < 8; ++j) {
                const int row = nb_ids[g * KK + k0 + j];
                r[j] = *(const float4*)&embed[(size_t)row * DD + lane * 4];
            }
            #pragma unroll
            for (int j = 0; j < 8; ++j) {
                acc.x += r[j].x; acc.y += r[j].y; acc.z += r[j].z; acc.w += r[j].w;
            }
        }
        const float inv = 1.0f / (float)KK;
        *(float4*)&As[n][lane * 4] = s;
        float4 m = make_float4(acc.x * inv, acc.y * inv, acc.z * inv, acc.w * inv);
        *(float4*)&An[n][lane * 4] = m;
    }
    __syncthreads();
    const int h = tid;
    {
        float acc[BN];
        #pragma unroll
        for (int n = 0; n < BN; ++n) acc[n] = 0.f;
        for (int d0 = 0; d0 < DD; d0 += 4) {
            const float w0 = Ws[(d0+0)*HH+h], w1 = Ws[(d0+1)*HH+h];
            const float w2 = Ws[(d0+2)*HH+h], w3 = Ws[(d0+3)*HH+h];
            #pragma unroll
            for (int n = 0; n < BN; ++n) {
                const float4 a = *(const float4*)&As[n][d0];
                acc[n] = fmaf(a.x,w0,acc[n]); acc[n] = fmaf(a.y,w1,acc[n]);
                acc[n] = fmaf(a.z,w2,acc[n]); acc[n] = fmaf(a.w,w3,acc[n]);
            }
        }
        const float b = bias[h];
        #pragma unroll
        for (int n = 0; n < BN; ++n) {
            const float v = acc[n] + b;
            out[(size_t)(g0+n)*(2*HH) + h] = v > 0.f ? v : 0.f;
        }
    }
    {
        float acc[BN];
        #pragma unroll
        for (int n = 0; n < BN; ++n) acc[n] = 0.f;
        for (int d0 = 0; d0 < DD; d0 += 4) {
            const float w0 = Wn[(d0+0)*HH+h], w1 = Wn[(d0+1)*HH+h];
            const float w2 = Wn[(d0+2)*HH+h], w3 = Wn[(d0+3)*HH+h];
            #pragma unroll
            for (int n = 0; n < BN; ++n) {
                const float4 a = *(const float4*)&An[n][d0];
                acc[n] = fmaf(a.x,w0,acc[n]); acc[n] = fmaf(a.y,w1,acc[n]);
                acc[n] = fmaf(a.z,w2,acc[n]); acc[n] = fmaf(a.w,w3,acc[n]);
            }
        }
        const float b = bias[HH + h];
        #pragma unroll
        for (int n = 0; n < BN; ++n) {
            const float v = acc[n] + b;
            out[(size_t)(g0+n)*(2*HH) + HH + h] = v > 0.f ? v : 0.f;
        }
    }
}

extern "C" void kernel_launch(void* const* d_in, const int* in_sizes, int n_in,
                              void* d_out, int out_size, void* d_ws, size_t ws_size,
                              hipStream_t stream) {
    const float* embed    = (const float*)d_in[0];
    const int*   node_ids = (const int*)d_in[1];
    const int*   nb_ids   = (const int*)d_in[2];
    const float* Ws       = (const float*)d_in[3];
    const float* Wn       = (const float*)d_in[4];
    const float* bias     = (const float*)d_in[5];
    float*       out      = (float*)d_out;

    const size_t eb_bytes = (size_t)VV * DD * sizeof(ushort);   // 51.2 MB
    const size_t wt_bytes = 2ull * HH * DD * sizeof(ushort);    // 256 KB

    if (ws_size >= eb_bytes + wt_bytes) {
        ushort* Eb = (ushort*)d_ws;
        ushort* WT = (ushort*)((char*)d_ws + eb_bytes);
        k_conv<<<dim3(VV * DD / 2048), dim3(256), 0, stream>>>(embed, Eb);
        k_prep_w<<<dim3(DD / 64, HH / 64, 2), dim3(256), 0, stream>>>(Ws, Wn, WT);
        k_fused<1><<<dim3(NN / BN), dim3(256), 0, stream>>>(
            nullptr, Eb, node_ids, nb_ids, WT, bias, out);
    } else if (ws_size >= wt_bytes) {
        ushort* WT = (ushort*)d_ws;
        k_prep_w<<<dim3(DD / 64, HH / 64, 2), dim3(256), 0, stream>>>(Ws, Wn, WT);
        k_fused<0><<<dim3(NN / BN), dim3(256), 0, stream>>>(
            embed, nullptr, node_ids, nb_ids, WT, bias, out);
    } else {
        hetegraph_fused_kernel<<<dim3(NN / BN), dim3(256), 0, stream>>>(
            embed, node_ids, nb_ids, Ws, Wn, bias, out);
    }
}

// Round 7
// 101.994 us; speedup vs baseline: 1.7507x; 1.0615x over previous
//
#include <hip/hip_runtime.h>

#define VV 100000
#define NN 20000
#define KK 32
#define DD 256
#define HH 256
#define BN 16   // nodes per block in fallback fused kernels

typedef __attribute__((ext_vector_type(8))) short bf16x8;
typedef __attribute__((ext_vector_type(4))) float f32x4;

__device__ __forceinline__ ushort f2bf(float f) {
    // round-to-nearest-even f32 -> bf16
    uint u = __float_as_uint(f);
    return (ushort)((u + 0x7FFFu + ((u >> 16) & 1u)) >> 16);
}
__device__ __forceinline__ float bf2f(ushort u) {
    return __uint_as_float(((uint)u) << 16);
}

// ---------------- Kernel 0: embed table f32 -> bf16 ------------------------
__global__ __launch_bounds__(256) void k_conv(
    const float* __restrict__ E, ushort* __restrict__ Eb)
{
    const size_t i = ((size_t)blockIdx.x * 256 + threadIdx.x) * 8;
    const f32x4 a = __builtin_nontemporal_load((const f32x4*)&E[i]);
    const f32x4 b = __builtin_nontemporal_load((const f32x4*)&E[i + 4]);
    bf16x8 v;
    v[0] = (short)f2bf(a.x); v[1] = (short)f2bf(a.y);
    v[2] = (short)f2bf(a.z); v[3] = (short)f2bf(a.w);
    v[4] = (short)f2bf(b.x); v[5] = (short)f2bf(b.y);
    v[6] = (short)f2bf(b.z); v[7] = (short)f2bf(b.w);
    *(bf16x8*)&Eb[i] = v;
}

// ------- Kernel 1b: W [D][H] f32 -> fragment-major WTf [2][16][8][64][8] ---
// Slot (h, t, ks, lane): lane holds W[k = ks*32 + (lane>>4)*8 + e][t*16 + (lane&15)]
__global__ __launch_bounds__(256) void k_prep_wf(
    const float* __restrict__ Ws, const float* __restrict__ Wn,
    ushort* __restrict__ WTf)
{
    __shared__ float t[256][17];
    const int tid = threadIdx.x;
    const int h   = blockIdx.y;        // half (0=self,1=nb)
    const int tt  = blockIdx.x;        // col tile
    const float* src = h ? Wn : Ws;
    const int h0 = tt * 16;
    const int c = tid & 15, dr = tid >> 4;
    #pragma unroll
    for (int s = 0; s < 16; ++s) {
        const int d = s * 16 + dr;
        t[d][c] = src[(size_t)d * HH + h0 + c];
    }
    __syncthreads();
    const int fl = tid & 63, w = tid >> 6;
    const int r16 = fl & 15, kg = fl >> 4;
    #pragma unroll
    for (int p = 0; p < 2; ++p) {
        const int ks = w + p * 4;
        bf16x8 v;
        #pragma unroll
        for (int e = 0; e < 8; ++e)
            v[e] = (short)f2bf(t[ks * 32 + kg * 8 + e][r16]);
        *(bf16x8*)&WTf[(((size_t)(h * 16 + tt) * 8 + ks) * 64 + fl) * 8] = v;
    }
}

// ------- Kernel 1: W [D][H] f32 -> W^T [H][D] bf16 (for fallback tiers) ----
__global__ __launch_bounds__(256) void k_prep_w(
    const float* __restrict__ Ws, const float* __restrict__ Wn,
    ushort* __restrict__ WT)   // [2][H][D] bf16
{
    __shared__ float t[64][65];
    const int tid = threadIdx.x;
    const float* src = (blockIdx.z == 0) ? Ws : Wn;
    ushort* dst = WT + (size_t)blockIdx.z * HH * DD;
    const int d0 = blockIdx.x * 64, h0 = blockIdx.y * 64;

    const int hl = tid & 63, dq = tid >> 6;
    #pragma unroll
    for (int i = 0; i < 16; ++i) {
        const int dl = dq * 16 + i;
        t[dl][hl] = src[(size_t)(d0 + dl) * HH + h0 + hl];
    }
    __syncthreads();
    const int dl = tid & 63, hq = tid >> 6;
    #pragma unroll
    for (int i = 0; i < 16; ++i) {
        const int h2 = hq * 16 + i;
        dst[(size_t)(h0 + h2) * DD + d0 + dl] = f2bf(t[dl][h2]);
    }
}

// ------- Kernel 2: gather + mean-pool -> A fragment-major ------------------
// One node per wave. 17-deep load window: slot 0 = self row (both halves),
// slots 1..16: lo half = nb[j-1] (0..15), hi half = nb[j+15] (16..31).
// Lane l31 holds row elements [8*l31, 8*l31+8) == fragment (ks=l31>>2, kg=l31&3).
// A layout: [tile][half][ks][64 lanes][8]; half 0 = self, half 1 = pooled.
__global__ __launch_bounds__(256, 4) void k_gatherf(
    const ushort* __restrict__ Eb,
    const int*    __restrict__ node_ids,
    const int*    __restrict__ nb_ids,
    ushort*       __restrict__ A)
{
    const int wv   = __builtin_amdgcn_readfirstlane((int)(threadIdx.x >> 6));
    const int lane = threadIdx.x & 63;
    const int sub  = lane >> 5;        // 0 = lo half-wave, 1 = hi half-wave
    const int l31  = lane & 31;
    const int g    = blockIdx.x * 4 + wv;
    const int base = g * KK;

    const int srow = node_ids[g];      // uniform -> s_load
    bf16x8 r[17];
    r[0] = *(const bf16x8*)&Eb[((size_t)(uint)srow << 8) + l31 * 8];
    #pragma unroll
    for (int j = 1; j <= 16; ++j) {
        const int rlo = nb_ids[base + j - 1];    // uniform -> s_load
        const int rhi = nb_ids[base + j + 15];   // uniform -> s_load
        const int row = sub ? rhi : rlo;
        r[j] = *(const bf16x8*)&Eb[((size_t)(uint)row << 8) + l31 * 8];
    }

    float acc[8];
    #pragma unroll
    for (int e = 0; e < 8; ++e) acc[e] = 0.f;
    #pragma unroll
    for (int j = 1; j <= 16; ++j) {
        #pragma unroll
        for (int e = 0; e < 8; ++e)
            acc[e] += bf2f((ushort)r[j][e]);
    }
    // lo half holds sum(nb 0..15), hi half holds sum(nb 16..31) -> combine
    #pragma unroll
    for (int e = 0; e < 8; ++e)
        acc[e] += __shfl_xor(acc[e], 32);

    const float inv = 1.0f / (float)KK;
    bf16x8 nv;
    #pragma unroll
    for (int e = 0; e < 8; ++e)
        nv[e] = (short)f2bf(acc[e] * inv);

    const int tile = g >> 4, rr = g & 15;
    const int ks = l31 >> 2, kgw = l31 & 3;
    const size_t dst = (((size_t)(tile * 2 + sub) * 8 + ks) * 64 + kgw * 16 + rr) * 8;
    *(bf16x8*)&A[dst] = sub ? nv : r[0];
}

// ------- Kernel 3: GEMM, fully-coalesced fragment loads --------------------
__global__ __launch_bounds__(256, 4) void k_gemmf(
    const ushort* __restrict__ A,     // [tiles][2][8][64][8]
    const ushort* __restrict__ WTf,   // [2][16][8][64][8]
    const float*  __restrict__ bias,  // [2H]
    float*        __restrict__ out)   // [N][2H]
{
    const int wv   = __builtin_amdgcn_readfirstlane((int)(threadIdx.x >> 6));
    const int lane = threadIdx.x & 63;
    const int tile = blockIdx.x;
    const int half = wv >> 1, qt = wv & 1;
    const int r16 = lane & 15, kg = lane >> 4;

    bf16x8 a[8];
    #pragma unroll
    for (int ks = 0; ks < 8; ++ks)
        a[ks] = *(const bf16x8*)&A[(((size_t)(tile * 2 + half) * 8 + ks) * 64 + lane) * 8];

    f32x4 accs[8];
    #pragma unroll
    for (int ct = 0; ct < 8; ++ct) {
        const int t = qt * 8 + ct;
        f32x4 acc = {0.f, 0.f, 0.f, 0.f};
        #pragma unroll
        for (int ks = 0; ks < 8; ++ks) {
            const bf16x8 b = *(const bf16x8*)&WTf[(((size_t)(half * 16 + t) * 8 + ks) * 64 + lane) * 8];
            acc = __builtin_amdgcn_mfma_f32_16x16x32_bf16(a[ks], b, acc, 0, 0, 0);
        }
        accs[ct] = acc;
    }

    #pragma unroll
    for (int ct = 0; ct < 8; ++ct) {
        const int cglob = half * HH + (qt * 8 + ct) * 16 + r16;
        const float bv = bias[cglob];
        #pragma unroll
        for (int r = 0; r < 4; ++r) {
            const float v = accs[ct][r] + bv;
            out[(size_t)(tile * 16 + kg * 4 + r) * (2 * HH) + cglob] = v > 0.f ? v : 0.f;
        }
    }
}

// ------- Fallback: fused gather + pool + GEMM (round-6, proven) ------------
template<int EBF16>
__global__ __launch_bounds__(256, 4) void k_fused(
    const float*  __restrict__ Ef,
    const ushort* __restrict__ Eb,
    const int*    __restrict__ node_ids,
    const int*    __restrict__ nb_ids,
    const ushort* __restrict__ WT,       // [2][H][D] bf16
    const float*  __restrict__ bias,
    float*        __restrict__ out)
{
    __shared__ ushort As[BN][DD];
    __shared__ ushort An[BN][DD];
    const int tid  = threadIdx.x;
    const int wave = tid >> 6;
    const int lane = tid & 63;
    const int g0   = blockIdx.x * BN;

    if (EBF16) {
        const int sub = lane >> 5;
        const int l31 = lane & 31;
        const uint boff = (uint)l31 * 16;
        for (int n = wave; n < BN; n += 4) {
            const int g = g0 + n;
            const int base = g * KK;
            const uint swz = ((uint)(n & 7)) << 4;
            const int srow = node_ids[g];
            const bf16x8 sv = *(const bf16x8*)&Eb[((size_t)(uint)srow << 8) + l31 * 8];
            bf16x8 r[16];
            #pragma unroll
            for (int j = 0; j < 16; ++j) {
                const int rlo = nb_ids[base + 2 * j];
                const int rhi = nb_ids[base + 2 * j + 1];
                const int row = sub ? rhi : rlo;
                r[j] = *(const bf16x8*)&Eb[((size_t)(uint)row << 8) + l31 * 8];
            }
            float acc[8];
            #pragma unroll
            for (int e = 0; e < 8; ++e) acc[e] = 0.f;
            #pragma unroll
            for (int j = 0; j < 16; ++j) {
                #pragma unroll
                for (int e = 0; e < 8; ++e)
                    acc[e] += bf2f((ushort)r[j][e]);
            }
            #pragma unroll
            for (int e = 0; e < 8; ++e)
                acc[e] += __shfl_xor(acc[e], 32);
            const float inv = 1.0f / (float)KK;
            bf16x8 nv;
            #pragma unroll
            for (int e = 0; e < 8; ++e)
                nv[e] = (short)f2bf(acc[e] * inv);
            if (sub == 0) {
                *(bf16x8*)((char*)&As[n][0] + (boff ^ swz)) = sv;
            } else {
                *(bf16x8*)((char*)&An[n][0] + (boff ^ swz)) = nv;
            }
        }
    } else {
        for (int n = wave; n < BN; n += 4) {
            const int g = g0 + n;
            const int srow = node_ids[g];
            const uint swz  = ((uint)(n & 7)) << 4;
            const uint boff = (uint)lane * 8;
            const float4 s = *(const float4*)&Ef[(size_t)srow * DD + lane * 4];
            ushort4 sv = make_ushort4(f2bf(s.x), f2bf(s.y), f2bf(s.z), f2bf(s.w));
            float4 acc = make_float4(0.f, 0.f, 0.f, 0.f);
            #pragma unroll
            for (int k0 = 0; k0 < KK; k0 += 8) {
                float4 r[8];
                #pragma unroll
                for (int j = 0; j < 8; ++j) {
                    const int row = nb_ids[g * KK + k0 + j];
                    r[j] = *(const float4*)&Ef[(size_t)row * DD + lane * 4];
                }
                #pragma unroll
                for (int j = 0; j < 8; ++j) {
                    acc.x += r[j].x; acc.y += r[j].y;
                    acc.z += r[j].z; acc.w += r[j].w;
                }
            }
            const float inv = 1.0f / (float)KK;
            const ushort4 nv = make_ushort4(f2bf(acc.x * inv), f2bf(acc.y * inv),
                                            f2bf(acc.z * inv), f2bf(acc.w * inv));
            *(ushort4*)((char*)&As[n][0] + (boff ^ swz)) = sv;
            *(ushort4*)((char*)&An[n][0] + (boff ^ swz)) = nv;
        }
    }
    __syncthreads();

    const int half = wave >> 1;
    const int colq = (wave & 1) * 128;
    const int r16  = lane & 15;
    const int kg   = lane >> 4;
    const uint rswz = ((uint)(r16 & 7)) << 4;
    const char* Arow = (const char*)(half ? &An[r16][0] : &As[r16][0]);

    bf16x8 a[8];
    #pragma unroll
    for (int ks = 0; ks < 8; ++ks) {
        const uint off = (uint)(ks * 64 + kg * 16);
        a[ks] = *(const bf16x8*)(Arow + (off ^ rswz));
    }

    const ushort* Wb = WT + (size_t)half * HH * DD;
    f32x4 accs[8];
    #pragma unroll
    for (int ct = 0; ct < 8; ++ct) {
        const int c = colq + ct * 16 + r16;
        const ushort* Bb = Wb + (size_t)c * DD + kg * 8;
        f32x4 acc = {0.f, 0.f, 0.f, 0.f};
        #pragma unroll
        for (int ks = 0; ks < 8; ++ks) {
            const bf16x8 b = *(const bf16x8*)(Bb + ks * 32);
            acc = __builtin_amdgcn_mfma_f32_16x16x32_bf16(a[ks], b, acc, 0, 0, 0);
        }
        accs[ct] = acc;
    }

    #pragma unroll
    for (int ct = 0; ct < 8; ++ct) {
        const int cglob = half * HH + colq + ct * 16 + r16;
        const float bv = bias[cglob];
        #pragma unroll
        for (int r = 0; r < 4; ++r) {
            const float v = accs[ct][r] + bv;
            out[(size_t)(g0 + kg * 4 + r) * (2 * HH) + cglob] = v > 0.f ? v : 0.f;
        }
    }
}

// ---------------- Ultimate fallback (round-1 fused fp32 kernel) ------------
__global__ __launch_bounds__(256, 4) void hetegraph_fused_kernel(
    const float* __restrict__ embed, const int* __restrict__ node_ids,
    const int* __restrict__ nb_ids, const float* __restrict__ Ws,
    const float* __restrict__ Wn, const float* __restrict__ bias,
    float* __restrict__ out)
{
    __shared__ float As[BN][DD];
    __shared__ float An[BN][DD];
    const int tid = threadIdx.x, wave = tid >> 6, lane = tid & 63;
    const int g0 = blockIdx.x * BN;
    for (int n = wave; n < BN; n += 4) {
        const int g = g0 + n;
        const int self_row = node_ids[g];
        const float4 s = *(const float4*)&embed[(size_t)self_row * DD + lane * 4];
        float4 acc = make_float4(0.f, 0.f, 0.f, 0.f);
        for (int k0 = 0; k0 < KK; k0 += 8) {
            float4 r[8];
            #pragma unroll
            for (int j = 0; j < 8; ++j) {
                const int row = nb_ids[g * KK + k0 + j];
                r[j] = *(const float4*)&embed[(size_t)row * DD + lane * 4];
            }
            #pragma unroll
            for (int j = 0; j < 8; ++j) {
                acc.x += r[j].x; acc.y += r[j].y; acc.z += r[j].z; acc.w += r[j].w;
            }
        }
        const float inv = 1.0f / (float)KK;
        *(float4*)&As[n][lane * 4] = s;
        float4 m = make_float4(acc.x * inv, acc.y * inv, acc.z * inv, acc.w * inv);
        *(float4*)&An[n][lane * 4] = m;
    }
    __syncthreads();
    const int h = tid;
    {
        float acc[BN];
        #pragma unroll
        for (int n = 0; n < BN; ++n) acc[n] = 0.f;
        for (int d0 = 0; d0 < DD; d0 += 4) {
            const float w0 = Ws[(d0+0)*HH+h], w1 = Ws[(d0+1)*HH+h];
            const float w2 = Ws[(d0+2)*HH+h], w3 = Ws[(d0+3)*HH+h];
            #pragma unroll
            for (int n = 0; n < BN; ++n) {
                const float4 a = *(const float4*)&As[n][d0];
                acc[n] = fmaf(a.x,w0,acc[n]); acc[n] = fmaf(a.y,w1,acc[n]);
                acc[n] = fmaf(a.z,w2,acc[n]); acc[n] = fmaf(a.w,w3,acc[n]);
            }
        }
        const float b = bias[h];
        #pragma unroll
        for (int n = 0; n < BN; ++n) {
            const float v = acc[n] + b;
            out[(size_t)(g0+n)*(2*HH) + h] = v > 0.f ? v : 0.f;
        }
    }
    {
        float acc[BN];
        #pragma unroll
        for (int n = 0; n < BN; ++n) acc[n] = 0.f;
        for (int d0 = 0; d0 < DD; d0 += 4) {
            const float w0 = Wn[(d0+0)*HH+h], w1 = Wn[(d0+1)*HH+h];
            const float w2 = Wn[(d0+2)*HH+h], w3 = Wn[(d0+3)*HH+h];
            #pragma unroll
            for (int n = 0; n < BN; ++n) {
                const float4 a = *(const float4*)&An[n][d0];
                acc[n] = fmaf(a.x,w0,acc[n]); acc[n] = fmaf(a.y,w1,acc[n]);
                acc[n] = fmaf(a.z,w2,acc[n]); acc[n] = fmaf(a.w,w3,acc[n]);
            }
        }
        const float b = bias[HH + h];
        #pragma unroll
        for (int n = 0; n < BN; ++n) {
            const float v = acc[n] + b;
            out[(size_t)(g0+n)*(2*HH) + HH + h] = v > 0.f ? v : 0.f;
        }
    }
}

extern "C" void kernel_launch(void* const* d_in, const int* in_sizes, int n_in,
                              void* d_out, int out_size, void* d_ws, size_t ws_size,
                              hipStream_t stream) {
    const float* embed    = (const float*)d_in[0];
    const int*   node_ids = (const int*)d_in[1];
    const int*   nb_ids   = (const int*)d_in[2];
    const float* Ws       = (const float*)d_in[3];
    const float* Wn       = (const float*)d_in[4];
    const float* bias     = (const float*)d_in[5];
    float*       out      = (float*)d_out;

    const size_t eb_bytes  = (size_t)VV * DD * sizeof(ushort);            // 51.2 MB
    const size_t wtf_bytes = 2ull * 16 * 8 * 64 * 8 * sizeof(ushort);     // 256 KB
    const size_t af_bytes  = (size_t)(NN / 16) * 2 * 8 * 64 * 8 * sizeof(ushort); // 20.48 MB
    const size_t wt_bytes  = 2ull * HH * DD * sizeof(ushort);             // 256 KB

    if (ws_size >= eb_bytes + wtf_bytes + af_bytes) {
        ushort* Eb  = (ushort*)d_ws;
        ushort* WTf = (ushort*)((char*)d_ws + eb_bytes);
        ushort* Af  = (ushort*)((char*)d_ws + eb_bytes + wtf_bytes);
        k_prep_wf<<<dim3(16, 2), dim3(256), 0, stream>>>(Ws, Wn, WTf);
        k_conv<<<dim3(VV * DD / 2048), dim3(256), 0, stream>>>(embed, Eb);
        k_gatherf<<<dim3(NN / 4), dim3(256), 0, stream>>>(Eb, node_ids, nb_ids, Af);
        k_gemmf<<<dim3(NN / 16), dim3(256), 0, stream>>>(Af, WTf, bias, out);
    } else if (ws_size >= eb_bytes + wt_bytes) {
        ushort* Eb = (ushort*)d_ws;
        ushort* WT = (ushort*)((char*)d_ws + eb_bytes);
        k_conv<<<dim3(VV * DD / 2048), dim3(256), 0, stream>>>(embed, Eb);
        k_prep_w<<<dim3(DD / 64, HH / 64, 2), dim3(256), 0, stream>>>(Ws, Wn, WT);
        k_fused<1><<<dim3(NN / BN), dim3(256), 0, stream>>>(
            nullptr, Eb, node_ids, nb_ids, WT, bias, out);
    } else if (ws_size >= wt_bytes) {
        ushort* WT = (ushort*)d_ws;
        k_prep_w<<<dim3(DD / 64, HH / 64, 2), dim3(256), 0, stream>>>(Ws, Wn, WT);
        k_fused<0><<<dim3(NN / BN), dim3(256), 0, stream>>>(
            embed, nullptr, node_ids, nb_ids, WT, bias, out);
    } else {
        hetegraph_fused_kernel<<<dim3(NN / BN), dim3(256), 0, stream>>>(
            embed, node_ids, nb_ids, Ws, Wn, bias, out);
    }
}